// Round 15
// baseline (394.951 us; speedup 1.0000x reference)
//
#include <hip/hip_runtime.h>
#include <math.h>

#define EPS_LN   1e-5f
#define NEG_SLOPE 0.2f
#define NUM_GRAPHS 64
#define POOL_SPLIT 16

// ---------------- reduction helpers ----------------
__device__ __forceinline__ float red64(float v) {
    #pragma unroll
    for (int m = 32; m > 0; m >>= 1) v += __shfl_xor(v, m);
    return v;
}

// ---------------- we_dot[h] = sum_c We[h*C+c] * a_e[h*C+c], both layers ----------------
__global__ __launch_bounds__(256) void k_prep(
    const float* __restrict__ We0, const float* __restrict__ ae0,
    const float* __restrict__ We1, const float* __restrict__ ae1,
    float* __restrict__ wedot0, float* __restrict__ wedot1)
{
    __shared__ float red[256];
    int t = threadIdx.x;
    red[t] = We0[t] * ae0[t];
    __syncthreads();
    for (int s = 32; s > 0; s >>= 1) { if ((t & 63) < s) red[t] += red[t + s]; __syncthreads(); }
    if ((t & 63) == 0) wedot0[t >> 6] = red[t];
    __syncthreads();
    red[t] = (t < 128) ? We1[t] * ae1[t] : 0.f;
    __syncthreads();
    for (int s = 16; s > 0; s >>= 1) { if (t < 128 && (t & 31) < s) red[t] += red[t + s]; __syncthreads(); }
    if (t < 128 && (t & 31) == 0) wedot1[t >> 5] = red[t];
}

// ---------------- edge_attr mean (two-stage deterministic) ----------------
__global__ __launch_bounds__(256) void k_esum_partial(const float* __restrict__ ea, float* __restrict__ part, int E)
{
    __shared__ float red[256];
    int t = threadIdx.x;
    float s = 0.f;
    for (int i = blockIdx.x * 256 + t; i < E; i += gridDim.x * 256) s += ea[i];
    red[t] = s; __syncthreads();
    for (int k = 128; k > 0; k >>= 1) { if (t < k) red[t] += red[t + k]; __syncthreads(); }
    if (t == 0) part[blockIdx.x] = red[0];
}
__global__ __launch_bounds__(256) void k_esum_final(const float* __restrict__ part, int B, float* __restrict__ mean_out, int E)
{
    __shared__ float red[256];
    int t = threadIdx.x;
    red[t] = (t < B) ? part[t] : 0.f; __syncthreads();
    for (int k = 128; k > 0; k >>= 1) { if (t < k) red[t] += red[t + k]; __syncthreads(); }
    if (t == 0) *mean_out = red[0] / (float)E;
}

// ---------------- CSR build (dst-indexed, includes self-loops as edge ids E..E+N-1) ----------------
__global__ __launch_bounds__(256) void k_counts_init(int* __restrict__ counts, int N)
{
    int t = blockIdx.x * 256 + threadIdx.x;
    if (t < N) counts[t] = 1;   // self-loop
}
__global__ __launch_bounds__(256) void k_count(const int* __restrict__ dst, int* __restrict__ counts, int E)
{
    int e = blockIdx.x * 256 + threadIdx.x;
    if (e < E) atomicAdd(&counts[dst[e]], 1);
}
// chunked exclusive scan over counts[0..N) -> row_ptr ; chunk = 1024
__global__ __launch_bounds__(256) void k_scan_partial(const int* __restrict__ counts, int* __restrict__ bsum, int N)
{
    __shared__ int red[256];
    int b = blockIdx.x, t = threadIdx.x;
    int base = b * 1024 + t * 4;
    int s = 0;
    #pragma unroll
    for (int i = 0; i < 4; ++i) { int idx = base + i; if (idx < N) s += counts[idx]; }
    red[t] = s; __syncthreads();
    for (int k = 128; k > 0; k >>= 1) { if (t < k) red[t] += red[t + k]; __syncthreads(); }
    if (t == 0) bsum[b] = red[0];
}
__global__ __launch_bounds__(64) void k_scan_bsums(const int* __restrict__ bsum, int* __restrict__ bpre, int B)
{
    __shared__ int s[64];
    int t = threadIdx.x;
    int v = (t < B) ? bsum[t] : 0;
    s[t] = v; __syncthreads();
    for (int off = 1; off < 64; off <<= 1) {
        int u = (t >= off) ? s[t - off] : 0; __syncthreads();
        s[t] += u; __syncthreads();
    }
    if (t < B) bpre[t] = s[t] - v;  // exclusive
}
// also writes cursor[] = row_ptr[] (merged former k_cursor_init)
__global__ __launch_bounds__(256) void k_scan_chunk(
    const int* __restrict__ counts, const int* __restrict__ bpre,
    int* __restrict__ row_ptr, int* __restrict__ cursor, int N, int E2)
{
    __shared__ int s[256];
    int b = blockIdx.x, t = threadIdx.x;
    int base = b * 1024 + t * 4;
    int l0 = (base + 0 < N) ? counts[base + 0] : 0;
    int l1 = (base + 1 < N) ? counts[base + 1] : 0;
    int l2 = (base + 2 < N) ? counts[base + 2] : 0;
    int l3 = (base + 3 < N) ? counts[base + 3] : 0;
    int lsum = l0 + l1 + l2 + l3;
    s[t] = lsum; __syncthreads();
    for (int off = 1; off < 256; off <<= 1) {
        int u = (t >= off) ? s[t - off] : 0; __syncthreads();
        s[t] += u; __syncthreads();
    }
    int run = bpre[b] + s[t] - lsum;
    if (base + 0 < N) { row_ptr[base + 0] = run; cursor[base + 0] = run; } run += l0;
    if (base + 1 < N) { row_ptr[base + 1] = run; cursor[base + 1] = run; } run += l1;
    if (base + 2 < N) { row_ptr[base + 2] = run; cursor[base + 2] = run; } run += l2;
    if (base + 3 < N) { row_ptr[base + 3] = run; cursor[base + 3] = run; }
    if (b == 0 && t == 0) row_ptr[N] = E2;
}
__global__ __launch_bounds__(256) void k_place(
    const int* __restrict__ dst, int* __restrict__ cursor, int* __restrict__ eids, int E, int N)
{
    int e = blockIdx.x * 256 + threadIdx.x;
    if (e >= E + N) return;
    int d = (e < E) ? dst[e] : (e - E);
    int pos = atomicAdd(&cursor[d], 1);
    eids[pos] = e;
}
// deterministic canonical order: sort each row by edge id (rows are tiny, avg deg ~9)
__global__ __launch_bounds__(256) void k_rowsort(const int* __restrict__ row_ptr, int* __restrict__ eids, int N)
{
    int n = blockIdx.x * 256 + threadIdx.x;
    if (n >= N) return;
    int r0 = row_ptr[n], r1 = row_ptr[n + 1];
    for (int i = r0 + 1; i < r1; ++i) {
        int key = eids[i];
        int j = i - 1;
        while (j >= r0 && eids[j] > key) { eids[j + 1] = eids[j]; --j; }
        eids[j + 1] = key;
    }
}

// ---------------- GEMM0: x0 = (x@Win+bin) @ W0  — input_proj fused into staging ---
// 128-row x 128-col block (grid.y = col half q), 8x8 thread tile,
// Ht[32][128] XOR-swizzled + Wc[32][128] = 32 KB LDS. Staging computes
// h[n][k] = bin[k] + sum_f x[n][f]*Win[f][k] on the fly (Win/bin in LDS).
// Epilogue fuses layer-0 attn dots (global head = 2q+{0,1}).
__global__ __launch_bounds__(256) void k_gemm0(
    const float* __restrict__ x, const float* __restrict__ Win, const float* __restrict__ bin,
    const float* __restrict__ W0,
    const float* __restrict__ As, const float* __restrict__ Ad,
    float* __restrict__ x0, float* __restrict__ as0, float* __restrict__ ad0, int N)
{
    __shared__ float Wc[32 * 128];   // [k2][c]
    __shared__ float Ht[32 * 128];   // [k2][row ^ (k2&28)]
    __shared__ float Wi[6 * 64];     // input-proj weights
    __shared__ float bi[64];
    const int nb = blockIdx.x * 128;
    const int q  = blockIdx.y;       // 128-col half of W0
    const int t = threadIdx.x;
    const int tc = t & 15, tr = t >> 4;
    const int r0 = tr * 4, c0 = tc * 4;
    const int kg = t & 7, rb = t >> 3;
    if (t < 384 - 256) Wi[t + 256] = Win[t + 256];
    Wi[t < 256 ? t : 0] = Win[t < 256 ? t : 0];
    if (t < 64) bi[t] = bin[t];
    float asv[8], adv[8];
    #pragma unroll
    for (int j = 0; j < 8; ++j) {
        int col = q * 128 + c0 + ((j < 4) ? j : 60 + j);
        asv[j] = As[col]; adv[j] = Ad[col];
    }
    float acc[8][8] = {};
    #pragma unroll
    for (int kc = 0; kc < 2; ++kc) {
        __syncthreads();
        #pragma unroll
        for (int j = 0; j < 4; ++j) {          // stage Ht: rows rb+32j, k = kg*4+i
            int row = rb + j * 32;
            int n = nb + row;
            float hv[4] = {0.f, 0.f, 0.f, 0.f};
            if (n < N) {
                float xr[6];
                #pragma unroll
                for (int f = 0; f < 6; ++f) xr[f] = x[(size_t)n * 6 + f];
                #pragma unroll
                for (int i = 0; i < 4; ++i) {
                    int k = kc * 32 + kg * 4 + i;
                    float a = bi[k];
                    #pragma unroll
                    for (int f = 0; f < 6; ++f) a += xr[f] * Wi[f * 64 + k];
                    hv[i] = a;
                }
            }
            #pragma unroll
            for (int i = 0; i < 4; ++i) {
                int k = kg * 4 + i;
                Ht[k * 128 + (row ^ (k & 28))] = hv[i];
            }
        }
        #pragma unroll
        for (int it = 0; it < 4; ++it) {       // stage Wc (contiguous b128)
            int idx = t * 4 + it * 1024;
            int k2 = idx >> 7, c = idx & 127;
            *reinterpret_cast<float4*>(&Wc[idx]) =
                *reinterpret_cast<const float4*>(W0 + (size_t)(kc * 32 + k2) * 256 + q * 128 + c);
        }
        __syncthreads();
        #pragma unroll 4
        for (int k2 = 0; k2 < 32; ++k2) {
            int sw = k2 & 28;
            float4 hlo = *reinterpret_cast<const float4*>(&Ht[k2 * 128 + (r0 ^ sw)]);
            float4 hhi = *reinterpret_cast<const float4*>(&Ht[k2 * 128 + ((r0 + 64) ^ sw)]);
            float4 wlo = *reinterpret_cast<const float4*>(&Wc[k2 * 128 + c0]);
            float4 whi = *reinterpret_cast<const float4*>(&Wc[k2 * 128 + c0 + 64]);
            float hr[8] = {hlo.x, hlo.y, hlo.z, hlo.w, hhi.x, hhi.y, hhi.z, hhi.w};
            float wr[8] = {wlo.x, wlo.y, wlo.z, wlo.w, whi.x, whi.y, whi.z, whi.w};
            #pragma unroll
            for (int i = 0; i < 8; ++i)
                #pragma unroll
                for (int j = 0; j < 8; ++j)
                    acc[i][j] += hr[i] * wr[j];
        }
    }
    #pragma unroll
    for (int i = 0; i < 8; ++i) {
        int n = nb + ((i < 4) ? (r0 + i) : (r0 + 60 + i));
        if (n < N) {
            *reinterpret_cast<float4*>(x0 + (size_t)n * 256 + q * 128 + c0) =
                make_float4(acc[i][0], acc[i][1], acc[i][2], acc[i][3]);
            *reinterpret_cast<float4*>(x0 + (size_t)n * 256 + q * 128 + c0 + 64) =
                make_float4(acc[i][4], acc[i][5], acc[i][6], acc[i][7]);
        }
        float sA = acc[i][0] * asv[0] + acc[i][1] * asv[1] + acc[i][2] * asv[2] + acc[i][3] * asv[3];
        float sB = acc[i][4] * asv[4] + acc[i][5] * asv[5] + acc[i][6] * asv[6] + acc[i][7] * asv[7];
        float dA = acc[i][0] * adv[0] + acc[i][1] * adv[1] + acc[i][2] * adv[2] + acc[i][3] * adv[3];
        float dB = acc[i][4] * adv[4] + acc[i][5] * adv[5] + acc[i][6] * adv[6] + acc[i][7] * adv[7];
        #pragma unroll
        for (int off = 1; off <= 8; off <<= 1) {
            sA += __shfl_xor(sA, off); sB += __shfl_xor(sB, off);
            dA += __shfl_xor(dA, off); dB += __shfl_xor(dB, off);
        }
        if (tc == 0 && n < N) {
            as0[n * 4 + 2 * q] = sA; as0[n * 4 + 2 * q + 1] = sB;
            ad0[n * 4 + 2 * q] = dA; ad0[n * 4 + 2 * q + 1] = dB;
        }
    }
}

// ---------------- GEMM1: x1 = h0 @ W1  [N,256]@[256,128] ----------------
__global__ __launch_bounds__(256) void k_gemm1(
    const float* __restrict__ h0, const float* __restrict__ W1,
    const float* __restrict__ As, const float* __restrict__ Ad,
    float* __restrict__ x1, float* __restrict__ as1, float* __restrict__ ad1, int N)
{
    __shared__ float Wc[32 * 128];   // 16 KB, [k2][c]
    __shared__ float Ht[32 * 128];   // 16 KB, [k2][row ^ (k2&28)]
    const int nb = blockIdx.x * 128;
    const int t = threadIdx.x;
    const int tc = t & 15, tr = t >> 4;
    const int r0 = tr * 4, c0 = tc * 4;
    const int kg = t & 7, rb = t >> 3;         // Ht staging: k-group, row base
    float asv[8], adv[8];
    #pragma unroll
    for (int j = 0; j < 8; ++j) {
        int col = c0 + ((j < 4) ? j : 60 + j);
        asv[j] = As[col]; adv[j] = Ad[col];
    }
    float acc[8][8] = {};
    for (int kc = 0; kc < 8; ++kc) {
        __syncthreads();                       // Ht/Wc reuse guard
        #pragma unroll
        for (int j = 0; j < 4; ++j) {          // stage Ht: rows rb+32j, k = kg*4+i
            int row = rb + j * 32;
            int n = nb + row;
            float4 v = make_float4(0.f, 0.f, 0.f, 0.f);
            if (n < N)
                v = *reinterpret_cast<const float4*>(h0 + (size_t)n * 256 + kc * 32 + kg * 4);
            #pragma unroll
            for (int i = 0; i < 4; ++i) {
                int k = kg * 4 + i;
                float e = (i == 0) ? v.x : (i == 1) ? v.y : (i == 2) ? v.z : v.w;
                Ht[k * 128 + (row ^ (k & 28))] = e;
            }
        }
        #pragma unroll
        for (int it = 0; it < 4; ++it) {       // stage Wc (contiguous b128)
            int idx = t * 4 + it * 1024;
            int k2 = idx >> 7, c = idx & 127;
            *reinterpret_cast<float4*>(&Wc[idx]) =
                *reinterpret_cast<const float4*>(W1 + (size_t)(kc * 32 + k2) * 128 + c);
        }
        __syncthreads();
        #pragma unroll 4
        for (int k2 = 0; k2 < 32; ++k2) {
            int sw = k2 & 28;
            float4 hlo = *reinterpret_cast<const float4*>(&Ht[k2 * 128 + (r0 ^ sw)]);
            float4 hhi = *reinterpret_cast<const float4*>(&Ht[k2 * 128 + ((r0 + 64) ^ sw)]);
            float4 wlo = *reinterpret_cast<const float4*>(&Wc[k2 * 128 + c0]);
            float4 whi = *reinterpret_cast<const float4*>(&Wc[k2 * 128 + c0 + 64]);
            float hr[8] = {hlo.x, hlo.y, hlo.z, hlo.w, hhi.x, hhi.y, hhi.z, hhi.w};
            float wr[8] = {wlo.x, wlo.y, wlo.z, wlo.w, whi.x, whi.y, whi.z, whi.w};
            #pragma unroll
            for (int i = 0; i < 8; ++i)
                #pragma unroll
                for (int j = 0; j < 8; ++j)
                    acc[i][j] += hr[i] * wr[j];
        }
    }
    #pragma unroll
    for (int i = 0; i < 8; ++i) {
        int n = nb + ((i < 4) ? (r0 + i) : (r0 + 60 + i));   // r0+i or r0+64+(i-4)
        if (n < N) {
            *reinterpret_cast<float4*>(x1 + (size_t)n * 128 + c0) =
                make_float4(acc[i][0], acc[i][1], acc[i][2], acc[i][3]);
            *reinterpret_cast<float4*>(x1 + (size_t)n * 128 + c0 + 64) =
                make_float4(acc[i][4], acc[i][5], acc[i][6], acc[i][7]);
        }
        // fused attn dots
        float sA = acc[i][0] * asv[0] + acc[i][1] * asv[1] + acc[i][2] * asv[2] + acc[i][3] * asv[3];
        float sB = acc[i][4] * asv[4] + acc[i][5] * asv[5] + acc[i][6] * asv[6] + acc[i][7] * asv[7];
        float dA = acc[i][0] * adv[0] + acc[i][1] * adv[1] + acc[i][2] * adv[2] + acc[i][3] * adv[3];
        float dB = acc[i][4] * adv[4] + acc[i][5] * adv[5] + acc[i][6] * adv[6] + acc[i][7] * adv[7];
        #pragma unroll
        for (int off = 1; off <= 4; off <<= 1) {
            sA += __shfl_xor(sA, off); sB += __shfl_xor(sB, off);
            dA += __shfl_xor(dA, off); dB += __shfl_xor(dB, off);
        }
        if ((tc & 7) == 0 && n < N) {
            int hA = tc >> 3;
            as1[n * 4 + hA] = sA; as1[n * 4 + 2 + hA] = sB;
            ad1[n * 4 + hA] = dA; ad1[n * 4 + 2 + hA] = dB;
        }
    }
}

// ---------------- fused attention + aggregation + bias + LayerNorm (+ELU) -------
// one wave per dst node; attention computed INLINE per edge (as_n/ad_n gathers),
// flash-style online-softmax rescale (round-7 structure; VALU proven non-binding
// in round 11 — agg is gather-fabric-bound). No edgeprep pass, no alpha/srcp.
template <int HC, int VEC, bool DO_ELU>
__global__ __launch_bounds__(256) void k_agg(
    const float* __restrict__ xbuf, const int* __restrict__ row_ptr,
    const int* __restrict__ eids, const int* __restrict__ src,
    const float* __restrict__ eattr, const float* __restrict__ emean_p,
    const float* __restrict__ wedot,
    const float* __restrict__ as_n, const float* __restrict__ ad_n,
    const float* __restrict__ bias, const float* __restrict__ lng, const float* __restrict__ lnb,
    float* __restrict__ out, int N, int E)
{
    int n = (blockIdx.x * 256 + threadIdx.x) >> 6;
    int lane = threadIdx.x & 63;
    if (n >= N) return;
    int hh = lane >> 4;                 // head for this lane's channels (both layers)
    float wd = wedot[hh];
    float adv = ad_n[n * 4 + hh];
    float emean = *emean_p;
    int r0 = row_ptr[n], r1 = row_ptr[n + 1];

    float m = -INFINITY, s = 0.f;
    float acc[VEC] = {};
    for (int i = r0; i < r1; ++i) {
        int eid = eids[i];
        int sn; float ev;
        if (eid < E) { sn = src[eid]; ev = eattr[eid]; } else { sn = n; ev = emean; }
        float a = as_n[(size_t)sn * 4 + hh] + adv + ev * wd;
        a = (a > 0.f) ? a : NEG_SLOPE * a;
        float nm = fmaxf(m, a);
        float sc = __expf(m - nm);      // first iter: exp(-inf)=0
        float w  = __expf(a - nm);
        m = nm;
        s = s * sc + w;
        const float* xr = xbuf + (size_t)sn * HC + lane * VEC;
        if constexpr (VEC == 4) {
            float4 xv = *reinterpret_cast<const float4*>(xr);
            acc[0] = acc[0] * sc + w * xv.x;
            acc[1] = acc[1] * sc + w * xv.y;
            acc[2] = acc[2] * sc + w * xv.z;
            acc[3] = acc[3] * sc + w * xv.w;
        } else {
            float2 xv = *reinterpret_cast<const float2*>(xr);
            acc[0] = acc[0] * sc + w * xv.x;
            acc[1] = acc[1] * sc + w * xv.y;
        }
    }
    float inv = 1.f / (s + 1e-16f);

    // epilogue: normalize, +bias, LayerNorm over HC, optional ELU
    int ch0 = lane * VEC;
    float v[VEC];
    #pragma unroll
    for (int i = 0; i < VEC; ++i) v[i] = acc[i] * inv + bias[ch0 + i];
    float ls = 0.f;
    #pragma unroll
    for (int i = 0; i < VEC; ++i) ls += v[i];
    ls = red64(ls);
    float mu = ls / (float)HC;
    float lv = 0.f;
    #pragma unroll
    for (int i = 0; i < VEC; ++i) { float d = v[i] - mu; lv += d * d; }
    lv = red64(lv);
    float rs = rsqrtf(lv / (float)HC + EPS_LN);
    float o[VEC];
    #pragma unroll
    for (int i = 0; i < VEC; ++i) {
        float y = (v[i] - mu) * rs * lng[ch0 + i] + lnb[ch0 + i];
        if (DO_ELU) y = (y > 0.f) ? y : (expm1f(y));
        o[i] = y;
    }
    float* orow = out + (size_t)n * HC + ch0;
    if constexpr (VEC == 4) *reinterpret_cast<float4*>(orow) = make_float4(o[0], o[1], o[2], o[3]);
    else                    *reinterpret_cast<float2*>(orow) = make_float2(o[0], o[1]);
}

// ---------------- pooling (two-stage, deterministic) ----------------
__global__ __launch_bounds__(128) void k_bounds(const int* __restrict__ batch, int* __restrict__ gstart, int N)
{
    int g = threadIdx.x;
    if (g > NUM_GRAPHS) return;
    int lo = 0, hi = N;
    while (lo < hi) { int mid = (lo + hi) >> 1; if (batch[mid] < g) lo = mid + 1; else hi = mid; }
    gstart[g] = lo;
}
__global__ __launch_bounds__(128) void k_pool1(
    const float* __restrict__ h1, const int* __restrict__ gstart,
    float* __restrict__ psum, float* __restrict__ pmax)
{
    int g = blockIdx.x, sl = blockIdx.y, c = threadIdx.x;
    int s0 = gstart[g], s1 = gstart[g + 1];
    int cnt = s1 - s0;
    int chunk = (cnt + POOL_SPLIT - 1) / POOL_SPLIT;
    int b0 = s0 + sl * chunk;
    int b1 = min(b0 + chunk, s1);
    float sum = 0.f, mx = -INFINITY;
    for (int n = b0; n < b1; ++n) {
        float v = h1[(size_t)n * 128 + c];
        sum += v; mx = fmaxf(mx, v);
    }
    int o = (g * POOL_SPLIT + sl) * 128 + c;
    psum[o] = sum; pmax[o] = mx;
}
__global__ __launch_bounds__(128) void k_pool2(
    const float* __restrict__ psum, const float* __restrict__ pmax,
    const int* __restrict__ gstart, float* __restrict__ out)
{
    int g = blockIdx.x, c = threadIdx.x;
    float sum = 0.f, mx = -INFINITY;
    #pragma unroll
    for (int sl = 0; sl < POOL_SPLIT; ++sl) {
        int o = (g * POOL_SPLIT + sl) * 128 + c;
        sum += psum[o];
        mx = fmaxf(mx, pmax[o]);
    }
    int cnt = gstart[g + 1] - gstart[g];
    float mean = sum / fmaxf((float)cnt, 1.f);
    out[g * 128 + c] = 0.5f * (mean + mx);
}

// ---------------- host ----------------
extern "C" void kernel_launch(void* const* d_in, const int* in_sizes, int n_in,
                              void* d_out, int out_size, void* d_ws, size_t ws_size,
                              hipStream_t stream)
{
    const float* x     = (const float*)d_in[0];
    const int*   ei    = (const int*)d_in[1];
    const float* eattr = (const float*)d_in[2];
    const int*   batch = (const int*)d_in[3];
    const float* Win   = (const float*)d_in[4];
    const float* bin   = (const float*)d_in[5];
    const float* l0W   = (const float*)d_in[6];
    const float* l0We  = (const float*)d_in[7];
    const float* l0as  = (const float*)d_in[8];
    const float* l0ad  = (const float*)d_in[9];
    const float* l0ae  = (const float*)d_in[10];
    const float* l0b   = (const float*)d_in[11];
    const float* ln0g  = (const float*)d_in[12];
    const float* ln0b  = (const float*)d_in[13];
    const float* l1W   = (const float*)d_in[14];
    const float* l1We  = (const float*)d_in[15];
    const float* l1as  = (const float*)d_in[16];
    const float* l1ad  = (const float*)d_in[17];
    const float* l1ae  = (const float*)d_in[18];
    const float* l1b   = (const float*)d_in[19];
    const float* ln1g  = (const float*)d_in[20];
    const float* ln1b  = (const float*)d_in[21];

    const int N = in_sizes[0] / 6;
    const int E = in_sizes[1] / 2;
    const int E2 = E + N;
    const int* srcI = ei;
    const int* dstI = ei + E;

    char* ws = (char*)d_ws;
    size_t off = 0;
    auto alloc = [&](size_t bytes) -> char* {
        char* p = ws + off;
        off += (bytes + 255) & ~(size_t)255;
        return p;
    };

    float* x0     = (float*)alloc((size_t)N * 256 * 4);   // reused: x1 = first half, h1 = second half
    float* h0     = (float*)alloc((size_t)N * 256 * 4);
    float* as0    = (float*)alloc((size_t)N * 4 * 4);
    float* ad0    = (float*)alloc((size_t)N * 4 * 4);
    float* as1    = (float*)alloc((size_t)N * 4 * 4);
    float* ad1    = (float*)alloc((size_t)N * 4 * 4);
    int*   row_ptr= (int*)alloc((size_t)(N + 1) * 4);
    int*   counts = (int*)alloc((size_t)N * 4);
    int*   cursor = (int*)alloc((size_t)N * 4);
    int*   eids   = (int*)alloc((size_t)E2 * 4);
    int*   bsum   = (int*)alloc(64 * 4);
    int*   bpre   = (int*)alloc(64 * 4);
    float* epart  = (float*)alloc(256 * 4);
    float* emean  = (float*)alloc(4);
    float* wedot0 = (float*)alloc(16);
    float* wedot1 = (float*)alloc(16);
    int*   gstart = (int*)alloc((NUM_GRAPHS + 1) * 4);
    float* psum   = (float*)alloc((size_t)NUM_GRAPHS * POOL_SPLIT * 128 * 4);
    float* pmax   = (float*)alloc((size_t)NUM_GRAPHS * POOL_SPLIT * 128 * 4);

    float* x1 = x0;                       // [N,128], x0 dead by then
    float* h1 = x0 + (size_t)N * 128;     // [N,128]

    const int B = (N + 1023) / 1024;      // scan chunks

    // --- independent prep ---
    k_prep<<<1, 256, 0, stream>>>(l0We, l0ae, l1We, l1ae, wedot0, wedot1);
    k_esum_partial<<<256, 256, 0, stream>>>(eattr, epart, E);
    k_esum_final<<<1, 256, 0, stream>>>(epart, 256, emean, E);

    // --- CSR build (dst-indexed, deterministic) ---
    k_counts_init<<<(N + 255) / 256, 256, 0, stream>>>(counts, N);
    k_count<<<(E + 255) / 256, 256, 0, stream>>>(dstI, counts, E);
    k_scan_partial<<<B, 256, 0, stream>>>(counts, bsum, N);
    k_scan_bsums<<<1, 64, 0, stream>>>(bsum, bpre, B);
    k_scan_chunk<<<B, 256, 0, stream>>>(counts, bpre, row_ptr, cursor, N, E2);
    k_place<<<(E2 + 255) / 256, 256, 0, stream>>>(dstI, cursor, eids, E, N);
    k_rowsort<<<(N + 255) / 256, 256, 0, stream>>>(row_ptr, eids, N);

    // --- layer 0 ---
    k_gemm0<<<dim3((N + 127) / 128, 2), 256, 0, stream>>>(
        x, Win, bin, l0W, l0as, l0ad, x0, as0, ad0, N);
    k_agg<256, 4, true><<<(N + 3) / 4, 256, 0, stream>>>(
        x0, row_ptr, eids, srcI, eattr, emean, wedot0, as0, ad0,
        l0b, ln0g, ln0b, h0, N, E);

    // --- layer 1 ---
    k_gemm1<<<(N + 127) / 128, 256, 0, stream>>>(h0, l1W, l1as, l1ad, x1, as1, ad1, N);
    k_agg<128, 2, false><<<(N + 3) / 4, 256, 0, stream>>>(
        x1, row_ptr, eids, srcI, eattr, emean, wedot1, as1, ad1,
        l1b, ln1g, ln1b, h1, N, E);

    // --- pooling (two-stage) ---
    k_bounds<<<1, 128, 0, stream>>>(batch, gstart, N);
    k_pool1<<<dim3(NUM_GRAPHS, POOL_SPLIT), 128, 0, stream>>>(h1, gstart, psum, pmax);
    k_pool2<<<NUM_GRAPHS, 128, 0, stream>>>(psum, pmax, gstart, (float*)d_out);
}

// Round 16
// 388.633 us; speedup vs baseline: 1.0163x; 1.0163x over previous
//
#include <hip/hip_runtime.h>
#include <math.h>

#define EPS_LN   1e-5f
#define NEG_SLOPE 0.2f
#define NUM_GRAPHS 64
#define POOL_SPLIT 16

// ---------------- reduction helpers ----------------
__device__ __forceinline__ float red64(float v) {
    #pragma unroll
    for (int m = 32; m > 0; m >>= 1) v += __shfl_xor(v, m);
    return v;
}

// ---------------- we_dot[h] = sum_c We[h*C+c] * a_e[h*C+c], both layers ----------------
__global__ __launch_bounds__(256) void k_prep(
    const float* __restrict__ We0, const float* __restrict__ ae0,
    const float* __restrict__ We1, const float* __restrict__ ae1,
    float* __restrict__ wedot0, float* __restrict__ wedot1)
{
    __shared__ float red[256];
    int t = threadIdx.x;
    red[t] = We0[t] * ae0[t];
    __syncthreads();
    for (int s = 32; s > 0; s >>= 1) { if ((t & 63) < s) red[t] += red[t + s]; __syncthreads(); }
    if ((t & 63) == 0) wedot0[t >> 6] = red[t];
    __syncthreads();
    red[t] = (t < 128) ? We1[t] * ae1[t] : 0.f;
    __syncthreads();
    for (int s = 16; s > 0; s >>= 1) { if (t < 128 && (t & 31) < s) red[t] += red[t + s]; __syncthreads(); }
    if (t < 128 && (t & 31) == 0) wedot1[t >> 5] = red[t];
}

// ---------------- edge_attr mean (two-stage deterministic) ----------------
__global__ __launch_bounds__(256) void k_esum_partial(const float* __restrict__ ea, float* __restrict__ part, int E)
{
    __shared__ float red[256];
    int t = threadIdx.x;
    float s = 0.f;
    for (int i = blockIdx.x * 256 + t; i < E; i += gridDim.x * 256) s += ea[i];
    red[t] = s; __syncthreads();
    for (int k = 128; k > 0; k >>= 1) { if (t < k) red[t] += red[t + k]; __syncthreads(); }
    if (t == 0) part[blockIdx.x] = red[0];
}
__global__ __launch_bounds__(256) void k_esum_final(const float* __restrict__ part, int B, float* __restrict__ mean_out, int E)
{
    __shared__ float red[256];
    int t = threadIdx.x;
    red[t] = (t < B) ? part[t] : 0.f; __syncthreads();
    for (int k = 128; k > 0; k >>= 1) { if (t < k) red[t] += red[t + k]; __syncthreads(); }
    if (t == 0) *mean_out = red[0] / (float)E;
}

// ---------------- CSR build (dst-indexed, includes self-loops as edge ids E..E+N-1) ----------------
__global__ __launch_bounds__(256) void k_counts_init(int* __restrict__ counts, int N)
{
    int t = blockIdx.x * 256 + threadIdx.x;
    if (t < N) counts[t] = 1;   // self-loop
}
__global__ __launch_bounds__(256) void k_count(const int* __restrict__ dst, int* __restrict__ counts, int E)
{
    int e = blockIdx.x * 256 + threadIdx.x;
    if (e < E) atomicAdd(&counts[dst[e]], 1);
}
// chunked exclusive scan over counts[0..N) -> row_ptr ; chunk = 1024
__global__ __launch_bounds__(256) void k_scan_partial(const int* __restrict__ counts, int* __restrict__ bsum, int N)
{
    __shared__ int red[256];
    int b = blockIdx.x, t = threadIdx.x;
    int base = b * 1024 + t * 4;
    int s = 0;
    #pragma unroll
    for (int i = 0; i < 4; ++i) { int idx = base + i; if (idx < N) s += counts[idx]; }
    red[t] = s; __syncthreads();
    for (int k = 128; k > 0; k >>= 1) { if (t < k) red[t] += red[t + k]; __syncthreads(); }
    if (t == 0) bsum[b] = red[0];
}
__global__ __launch_bounds__(64) void k_scan_bsums(const int* __restrict__ bsum, int* __restrict__ bpre, int B)
{
    __shared__ int s[64];
    int t = threadIdx.x;
    int v = (t < B) ? bsum[t] : 0;
    s[t] = v; __syncthreads();
    for (int off = 1; off < 64; off <<= 1) {
        int u = (t >= off) ? s[t - off] : 0; __syncthreads();
        s[t] += u; __syncthreads();
    }
    if (t < B) bpre[t] = s[t] - v;  // exclusive
}
// also writes cursor[] = row_ptr[] (merged former k_cursor_init)
__global__ __launch_bounds__(256) void k_scan_chunk(
    const int* __restrict__ counts, const int* __restrict__ bpre,
    int* __restrict__ row_ptr, int* __restrict__ cursor, int N, int E2)
{
    __shared__ int s[256];
    int b = blockIdx.x, t = threadIdx.x;
    int base = b * 1024 + t * 4;
    int l0 = (base + 0 < N) ? counts[base + 0] : 0;
    int l1 = (base + 1 < N) ? counts[base + 1] : 0;
    int l2 = (base + 2 < N) ? counts[base + 2] : 0;
    int l3 = (base + 3 < N) ? counts[base + 3] : 0;
    int lsum = l0 + l1 + l2 + l3;
    s[t] = lsum; __syncthreads();
    for (int off = 1; off < 256; off <<= 1) {
        int u = (t >= off) ? s[t - off] : 0; __syncthreads();
        s[t] += u; __syncthreads();
    }
    int run = bpre[b] + s[t] - lsum;
    if (base + 0 < N) { row_ptr[base + 0] = run; cursor[base + 0] = run; } run += l0;
    if (base + 1 < N) { row_ptr[base + 1] = run; cursor[base + 1] = run; } run += l1;
    if (base + 2 < N) { row_ptr[base + 2] = run; cursor[base + 2] = run; } run += l2;
    if (base + 3 < N) { row_ptr[base + 3] = run; cursor[base + 3] = run; }
    if (b == 0 && t == 0) row_ptr[N] = E2;
}
__global__ __launch_bounds__(256) void k_place(
    const int* __restrict__ dst, int* __restrict__ cursor, int* __restrict__ eids, int E, int N)
{
    int e = blockIdx.x * 256 + threadIdx.x;
    if (e >= E + N) return;
    int d = (e < E) ? dst[e] : (e - E);
    int pos = atomicAdd(&cursor[d], 1);
    eids[pos] = e;
}
// deterministic canonical order: sort each row by edge id (rows are tiny, avg deg ~9)
__global__ __launch_bounds__(256) void k_rowsort(const int* __restrict__ row_ptr, int* __restrict__ eids, int N)
{
    int n = blockIdx.x * 256 + threadIdx.x;
    if (n >= N) return;
    int r0 = row_ptr[n], r1 = row_ptr[n + 1];
    for (int i = r0 + 1; i < r1; ++i) {
        int key = eids[i];
        int j = i - 1;
        while (j >= r0 && eids[j] > key) { eids[j + 1] = eids[j]; --j; }
        eids[j + 1] = key;
    }
}

// ---------------- GEMM0: x0 = (x@Win+bin) @ W0  — input_proj fused into staging ---
// 128-row x 128-col block (grid.y = col half q), 8x8 thread tile,
// Ht[32][128] XOR-swizzled + Wc[32][128] = 32 KB LDS. Staging computes
// h[n][k] = bin[k] + sum_f x[n][f]*Win[f][k] on the fly (Win/bin in LDS).
// Epilogue fuses layer-0 attn dots (global head = 2q+{0,1}).
__global__ __launch_bounds__(256) void k_gemm0(
    const float* __restrict__ x, const float* __restrict__ Win, const float* __restrict__ bin,
    const float* __restrict__ W0,
    const float* __restrict__ As, const float* __restrict__ Ad,
    float* __restrict__ x0, float* __restrict__ as0, float* __restrict__ ad0, int N)
{
    __shared__ float Wc[32 * 128];   // [k2][c]
    __shared__ float Ht[32 * 128];   // [k2][row ^ (k2&28)]
    __shared__ float Wi[6 * 64];     // input-proj weights
    __shared__ float bi[64];
    const int nb = blockIdx.x * 128;
    const int q  = blockIdx.y;       // 128-col half of W0
    const int t = threadIdx.x;
    const int tc = t & 15, tr = t >> 4;
    const int r0 = tr * 4, c0 = tc * 4;
    const int kg = t & 7, rb = t >> 3;
    if (t < 384 - 256) Wi[t + 256] = Win[t + 256];
    Wi[t < 256 ? t : 0] = Win[t < 256 ? t : 0];
    if (t < 64) bi[t] = bin[t];
    float asv[8], adv[8];
    #pragma unroll
    for (int j = 0; j < 8; ++j) {
        int col = q * 128 + c0 + ((j < 4) ? j : 60 + j);
        asv[j] = As[col]; adv[j] = Ad[col];
    }
    float acc[8][8] = {};
    #pragma unroll
    for (int kc = 0; kc < 2; ++kc) {
        __syncthreads();
        #pragma unroll
        for (int j = 0; j < 4; ++j) {          // stage Ht: rows rb+32j, k = kg*4+i
            int row = rb + j * 32;
            int n = nb + row;
            float hv[4] = {0.f, 0.f, 0.f, 0.f};
            if (n < N) {
                float xr[6];
                #pragma unroll
                for (int f = 0; f < 6; ++f) xr[f] = x[(size_t)n * 6 + f];
                #pragma unroll
                for (int i = 0; i < 4; ++i) {
                    int k = kc * 32 + kg * 4 + i;
                    float a = bi[k];
                    #pragma unroll
                    for (int f = 0; f < 6; ++f) a += xr[f] * Wi[f * 64 + k];
                    hv[i] = a;
                }
            }
            #pragma unroll
            for (int i = 0; i < 4; ++i) {
                int k = kg * 4 + i;
                Ht[k * 128 + (row ^ (k & 28))] = hv[i];
            }
        }
        #pragma unroll
        for (int it = 0; it < 4; ++it) {       // stage Wc (contiguous b128)
            int idx = t * 4 + it * 1024;
            int k2 = idx >> 7, c = idx & 127;
            *reinterpret_cast<float4*>(&Wc[idx]) =
                *reinterpret_cast<const float4*>(W0 + (size_t)(kc * 32 + k2) * 256 + q * 128 + c);
        }
        __syncthreads();
        #pragma unroll 4
        for (int k2 = 0; k2 < 32; ++k2) {
            int sw = k2 & 28;
            float4 hlo = *reinterpret_cast<const float4*>(&Ht[k2 * 128 + (r0 ^ sw)]);
            float4 hhi = *reinterpret_cast<const float4*>(&Ht[k2 * 128 + ((r0 + 64) ^ sw)]);
            float4 wlo = *reinterpret_cast<const float4*>(&Wc[k2 * 128 + c0]);
            float4 whi = *reinterpret_cast<const float4*>(&Wc[k2 * 128 + c0 + 64]);
            float hr[8] = {hlo.x, hlo.y, hlo.z, hlo.w, hhi.x, hhi.y, hhi.z, hhi.w};
            float wr[8] = {wlo.x, wlo.y, wlo.z, wlo.w, whi.x, whi.y, whi.z, whi.w};
            #pragma unroll
            for (int i = 0; i < 8; ++i)
                #pragma unroll
                for (int j = 0; j < 8; ++j)
                    acc[i][j] += hr[i] * wr[j];
        }
    }
    #pragma unroll
    for (int i = 0; i < 8; ++i) {
        int n = nb + ((i < 4) ? (r0 + i) : (r0 + 60 + i));
        if (n < N) {
            *reinterpret_cast<float4*>(x0 + (size_t)n * 256 + q * 128 + c0) =
                make_float4(acc[i][0], acc[i][1], acc[i][2], acc[i][3]);
            *reinterpret_cast<float4*>(x0 + (size_t)n * 256 + q * 128 + c0 + 64) =
                make_float4(acc[i][4], acc[i][5], acc[i][6], acc[i][7]);
        }
        float sA = acc[i][0] * asv[0] + acc[i][1] * asv[1] + acc[i][2] * asv[2] + acc[i][3] * asv[3];
        float sB = acc[i][4] * asv[4] + acc[i][5] * asv[5] + acc[i][6] * asv[6] + acc[i][7] * asv[7];
        float dA = acc[i][0] * adv[0] + acc[i][1] * adv[1] + acc[i][2] * adv[2] + acc[i][3] * adv[3];
        float dB = acc[i][4] * adv[4] + acc[i][5] * adv[5] + acc[i][6] * adv[6] + acc[i][7] * adv[7];
        #pragma unroll
        for (int off = 1; off <= 8; off <<= 1) {
            sA += __shfl_xor(sA, off); sB += __shfl_xor(sB, off);
            dA += __shfl_xor(dA, off); dB += __shfl_xor(dB, off);
        }
        if (tc == 0 && n < N) {
            as0[n * 4 + 2 * q] = sA; as0[n * 4 + 2 * q + 1] = sB;
            ad0[n * 4 + 2 * q] = dA; ad0[n * 4 + 2 * q + 1] = dB;
        }
    }
}

// ---------------- GEMM1: x1 = h0 @ W1  [N,256]@[256,128] ----------------
__global__ __launch_bounds__(256) void k_gemm1(
    const float* __restrict__ h0, const float* __restrict__ W1,
    const float* __restrict__ As, const float* __restrict__ Ad,
    float* __restrict__ x1, float* __restrict__ as1, float* __restrict__ ad1, int N)
{
    __shared__ float Wc[32 * 128];   // 16 KB, [k2][c]
    __shared__ float Ht[32 * 128];   // 16 KB, [k2][row ^ (k2&28)]
    const int nb = blockIdx.x * 128;
    const int t = threadIdx.x;
    const int tc = t & 15, tr = t >> 4;
    const int r0 = tr * 4, c0 = tc * 4;
    const int kg = t & 7, rb = t >> 3;         // Ht staging: k-group, row base
    float asv[8], adv[8];
    #pragma unroll
    for (int j = 0; j < 8; ++j) {
        int col = c0 + ((j < 4) ? j : 60 + j);
        asv[j] = As[col]; adv[j] = Ad[col];
    }
    float acc[8][8] = {};
    for (int kc = 0; kc < 8; ++kc) {
        __syncthreads();                       // Ht/Wc reuse guard
        #pragma unroll
        for (int j = 0; j < 4; ++j) {          // stage Ht: rows rb+32j, k = kg*4+i
            int row = rb + j * 32;
            int n = nb + row;
            float4 v = make_float4(0.f, 0.f, 0.f, 0.f);
            if (n < N)
                v = *reinterpret_cast<const float4*>(h0 + (size_t)n * 256 + kc * 32 + kg * 4);
            #pragma unroll
            for (int i = 0; i < 4; ++i) {
                int k = kg * 4 + i;
                float e = (i == 0) ? v.x : (i == 1) ? v.y : (i == 2) ? v.z : v.w;
                Ht[k * 128 + (row ^ (k & 28))] = e;
            }
        }
        #pragma unroll
        for (int it = 0; it < 4; ++it) {       // stage Wc (contiguous b128)
            int idx = t * 4 + it * 1024;
            int k2 = idx >> 7, c = idx & 127;
            *reinterpret_cast<float4*>(&Wc[idx]) =
                *reinterpret_cast<const float4*>(W1 + (size_t)(kc * 32 + k2) * 128 + c);
        }
        __syncthreads();
        #pragma unroll 4
        for (int k2 = 0; k2 < 32; ++k2) {
            int sw = k2 & 28;
            float4 hlo = *reinterpret_cast<const float4*>(&Ht[k2 * 128 + (r0 ^ sw)]);
            float4 hhi = *reinterpret_cast<const float4*>(&Ht[k2 * 128 + ((r0 + 64) ^ sw)]);
            float4 wlo = *reinterpret_cast<const float4*>(&Wc[k2 * 128 + c0]);
            float4 whi = *reinterpret_cast<const float4*>(&Wc[k2 * 128 + c0 + 64]);
            float hr[8] = {hlo.x, hlo.y, hlo.z, hlo.w, hhi.x, hhi.y, hhi.z, hhi.w};
            float wr[8] = {wlo.x, wlo.y, wlo.z, wlo.w, whi.x, whi.y, whi.z, whi.w};
            #pragma unroll
            for (int i = 0; i < 8; ++i)
                #pragma unroll
                for (int j = 0; j < 8; ++j)
                    acc[i][j] += hr[i] * wr[j];
        }
    }
    #pragma unroll
    for (int i = 0; i < 8; ++i) {
        int n = nb + ((i < 4) ? (r0 + i) : (r0 + 60 + i));   // r0+i or r0+64+(i-4)
        if (n < N) {
            *reinterpret_cast<float4*>(x1 + (size_t)n * 128 + c0) =
                make_float4(acc[i][0], acc[i][1], acc[i][2], acc[i][3]);
            *reinterpret_cast<float4*>(x1 + (size_t)n * 128 + c0 + 64) =
                make_float4(acc[i][4], acc[i][5], acc[i][6], acc[i][7]);
        }
        // fused attn dots
        float sA = acc[i][0] * asv[0] + acc[i][1] * asv[1] + acc[i][2] * asv[2] + acc[i][3] * asv[3];
        float sB = acc[i][4] * asv[4] + acc[i][5] * asv[5] + acc[i][6] * asv[6] + acc[i][7] * asv[7];
        float dA = acc[i][0] * adv[0] + acc[i][1] * adv[1] + acc[i][2] * adv[2] + acc[i][3] * adv[3];
        float dB = acc[i][4] * adv[4] + acc[i][5] * adv[5] + acc[i][6] * adv[6] + acc[i][7] * adv[7];
        #pragma unroll
        for (int off = 1; off <= 4; off <<= 1) {
            sA += __shfl_xor(sA, off); sB += __shfl_xor(sB, off);
            dA += __shfl_xor(dA, off); dB += __shfl_xor(dB, off);
        }
        if ((tc & 7) == 0 && n < N) {
            int hA = tc >> 3;
            as1[n * 4 + hA] = sA; as1[n * 4 + 2 + hA] = sB;
            ad1[n * 4 + hA] = dA; ad1[n * 4 + 2 + hA] = dB;
        }
    }
}

// ---------------- edge prep: resolved src + NORMALIZED-numerator weights ----
// wave per node, LANE per edge slot.
// Pass A: alpha (leakyrelu'd) -> global; track per-head MAX only (fmax, no exp).
// Butterfly-max. Pass B: w = exp(a-m), accumulate s, write w. Butterfly-sum;
// store sinv[n][h] = 1/(s+1e-16). Agg = pure gather + one final scale.
template <bool WRITE_SRC>
__global__ __launch_bounds__(256) void k_edgeprep(
    const int* __restrict__ row_ptr, const int* __restrict__ eids,
    const int* __restrict__ src, const float* __restrict__ eattr,
    const float* __restrict__ emean_p, const float* __restrict__ wedot,
    const float* __restrict__ as_n, const float* __restrict__ ad_n,
    int* __restrict__ srcp, float4* __restrict__ alpha, float* __restrict__ sinv,
    int N, int E)
{
    int n = (blockIdx.x * 256 + threadIdx.x) >> 6;
    int lane = threadIdx.x & 63;
    if (n >= N) return;
    float emean = *emean_p;
    float wd0 = wedot[0], wd1 = wedot[1], wd2 = wedot[2], wd3 = wedot[3];
    float adv0 = ad_n[n * 4 + 0], adv1 = ad_n[n * 4 + 1];
    float adv2 = ad_n[n * 4 + 2], adv3 = ad_n[n * 4 + 3];
    int r0 = row_ptr[n], r1 = row_ptr[n + 1];

    float m0 = -1e30f, m1 = -1e30f, m2 = -1e30f, m3 = -1e30f;
    for (int i = r0 + lane; i < r1; i += 64) {
        int eid = eids[i];
        int sn; float ev;
        if (eid < E) { sn = src[eid]; ev = eattr[eid]; } else { sn = n; ev = emean; }
        if (WRITE_SRC) srcp[i] = sn;
        const float* as4 = as_n + (size_t)sn * 4;
        float a0 = as4[0] + adv0 + ev * wd0;
        float a1 = as4[1] + adv1 + ev * wd1;
        float a2 = as4[2] + adv2 + ev * wd2;
        float a3 = as4[3] + adv3 + ev * wd3;
        a0 = (a0 > 0.f) ? a0 : NEG_SLOPE * a0;
        a1 = (a1 > 0.f) ? a1 : NEG_SLOPE * a1;
        a2 = (a2 > 0.f) ? a2 : NEG_SLOPE * a2;
        a3 = (a3 > 0.f) ? a3 : NEG_SLOPE * a3;
        m0 = fmaxf(m0, a0); m1 = fmaxf(m1, a1);
        m2 = fmaxf(m2, a2); m3 = fmaxf(m3, a3);
        alpha[i] = make_float4(a0, a1, a2, a3);
    }
    #pragma unroll
    for (int off = 32; off > 0; off >>= 1) {
        m0 = fmaxf(m0, __shfl_xor(m0, off));
        m1 = fmaxf(m1, __shfl_xor(m1, off));
        m2 = fmaxf(m2, __shfl_xor(m2, off));
        m3 = fmaxf(m3, __shfl_xor(m3, off));
    }
    float s0 = 0.f, s1 = 0.f, s2 = 0.f, s3 = 0.f;
    for (int i = r0 + lane; i < r1; i += 64) {
        float4 a = alpha[i];
        float w0 = __expf(a.x - m0), w1 = __expf(a.y - m1);
        float w2 = __expf(a.z - m2), w3 = __expf(a.w - m3);
        s0 += w0; s1 += w1; s2 += w2; s3 += w3;
        alpha[i] = make_float4(w0, w1, w2, w3);
    }
    #pragma unroll
    for (int off = 32; off > 0; off >>= 1) {
        s0 += __shfl_xor(s0, off); s1 += __shfl_xor(s1, off);
        s2 += __shfl_xor(s2, off); s3 += __shfl_xor(s3, off);
    }
    if (lane == 0) {
        sinv[n * 4 + 0] = 1.f / (s0 + 1e-16f);
        sinv[n * 4 + 1] = 1.f / (s1 + 1e-16f);
        sinv[n * 4 + 2] = 1.f / (s2 + 1e-16f);
        sinv[n * 4 + 3] = 1.f / (s3 + 1e-16f);
    }
}

// ---------------- fused edge aggregation + bias + LayerNorm (+ELU) ----------------
// one wave per dst node; pure gather-accumulate (weights pre-normalized numerators
// from k_edgeprep); final scale by sinv in epilogue.
template <int HC, int VEC, bool DO_ELU>
__global__ __launch_bounds__(256) void k_agg(
    const float* __restrict__ x, const int* __restrict__ row_ptr,
    const int* __restrict__ srcp, const float* __restrict__ alpha,
    const float* __restrict__ sinv,
    const float* __restrict__ bias, const float* __restrict__ lng, const float* __restrict__ lnb,
    float* __restrict__ out, int N)
{
    int n = (blockIdx.x * 256 + threadIdx.x) >> 6;
    int lane = threadIdx.x & 63;
    if (n >= N) return;
    int hh = lane >> 4;                 // head for this lane's channels (both layers)
    int r0 = row_ptr[n], r1 = row_ptr[n + 1];

    float acc[VEC] = {};
    for (int i = r0; i < r1; i += 8) {
        int cnt = min(r1 - i, 8);
        int sn[8]; float wv[8];
        #pragma unroll
        for (int j = 0; j < 8; ++j)
            if (j < cnt) { sn[j] = srcp[i + j]; wv[j] = alpha[(size_t)(i + j) * 4 + hh]; }
        #pragma unroll
        for (int j = 0; j < 8; ++j)
            if (j < cnt) {
                const float* xr = x + (size_t)sn[j] * HC + lane * VEC;
                if constexpr (VEC == 4) {
                    float4 xv = *reinterpret_cast<const float4*>(xr);
                    acc[0] += wv[j] * xv.x; acc[1] += wv[j] * xv.y;
                    acc[2] += wv[j] * xv.z; acc[3] += wv[j] * xv.w;
                } else {
                    float2 xv = *reinterpret_cast<const float2*>(xr);
                    acc[0] += wv[j] * xv.x; acc[1] += wv[j] * xv.y;
                }
            }
    }
    float inv = sinv[n * 4 + hh];

    // epilogue: normalize, +bias, LayerNorm over HC, optional ELU
    int ch0 = lane * VEC;
    float v[VEC];
    #pragma unroll
    for (int i = 0; i < VEC; ++i) v[i] = acc[i] * inv + bias[ch0 + i];
    float ls = 0.f;
    #pragma unroll
    for (int i = 0; i < VEC; ++i) ls += v[i];
    ls = red64(ls);
    float mu = ls / (float)HC;
    float lv = 0.f;
    #pragma unroll
    for (int i = 0; i < VEC; ++i) { float d = v[i] - mu; lv += d * d; }
    lv = red64(lv);
    float rs = rsqrtf(lv / (float)HC + EPS_LN);
    float o[VEC];
    #pragma unroll
    for (int i = 0; i < VEC; ++i) {
        float y = (v[i] - mu) * rs * lng[ch0 + i] + lnb[ch0 + i];
        if (DO_ELU) y = (y > 0.f) ? y : (expm1f(y));
        o[i] = y;
    }
    float* orow = out + (size_t)n * HC + ch0;
    if constexpr (VEC == 4) *reinterpret_cast<float4*>(orow) = make_float4(o[0], o[1], o[2], o[3]);
    else                    *reinterpret_cast<float2*>(orow) = make_float2(o[0], o[1]);
}

// ---------------- pooling (two-stage, deterministic) ----------------
__global__ __launch_bounds__(128) void k_bounds(const int* __restrict__ batch, int* __restrict__ gstart, int N)
{
    int g = threadIdx.x;
    if (g > NUM_GRAPHS) return;
    int lo = 0, hi = N;
    while (lo < hi) { int mid = (lo + hi) >> 1; if (batch[mid] < g) lo = mid + 1; else hi = mid; }
    gstart[g] = lo;
}
__global__ __launch_bounds__(128) void k_pool1(
    const float* __restrict__ h1, const int* __restrict__ gstart,
    float* __restrict__ psum, float* __restrict__ pmax)
{
    int g = blockIdx.x, sl = blockIdx.y, c = threadIdx.x;
    int s0 = gstart[g], s1 = gstart[g + 1];
    int cnt = s1 - s0;
    int chunk = (cnt + POOL_SPLIT - 1) / POOL_SPLIT;
    int b0 = s0 + sl * chunk;
    int b1 = min(b0 + chunk, s1);
    float sum = 0.f, mx = -INFINITY;
    for (int n = b0; n < b1; ++n) {
        float v = h1[(size_t)n * 128 + c];
        sum += v; mx = fmaxf(mx, v);
    }
    int o = (g * POOL_SPLIT + sl) * 128 + c;
    psum[o] = sum; pmax[o] = mx;
}
__global__ __launch_bounds__(128) void k_pool2(
    const float* __restrict__ psum, const float* __restrict__ pmax,
    const int* __restrict__ gstart, float* __restrict__ out)
{
    int g = blockIdx.x, c = threadIdx.x;
    float sum = 0.f, mx = -INFINITY;
    #pragma unroll
    for (int sl = 0; sl < POOL_SPLIT; ++sl) {
        int o = (g * POOL_SPLIT + sl) * 128 + c;
        sum += psum[o];
        mx = fmaxf(mx, pmax[o]);
    }
    int cnt = gstart[g + 1] - gstart[g];
    float mean = sum / fmaxf((float)cnt, 1.f);
    out[g * 128 + c] = 0.5f * (mean + mx);
}

// ---------------- host ----------------
extern "C" void kernel_launch(void* const* d_in, const int* in_sizes, int n_in,
                              void* d_out, int out_size, void* d_ws, size_t ws_size,
                              hipStream_t stream)
{
    const float* x     = (const float*)d_in[0];
    const int*   ei    = (const int*)d_in[1];
    const float* eattr = (const float*)d_in[2];
    const int*   batch = (const int*)d_in[3];
    const float* Win   = (const float*)d_in[4];
    const float* bin   = (const float*)d_in[5];
    const float* l0W   = (const float*)d_in[6];
    const float* l0We  = (const float*)d_in[7];
    const float* l0as  = (const float*)d_in[8];
    const float* l0ad  = (const float*)d_in[9];
    const float* l0ae  = (const float*)d_in[10];
    const float* l0b   = (const float*)d_in[11];
    const float* ln0g  = (const float*)d_in[12];
    const float* ln0b  = (const float*)d_in[13];
    const float* l1W   = (const float*)d_in[14];
    const float* l1We  = (const float*)d_in[15];
    const float* l1as  = (const float*)d_in[16];
    const float* l1ad  = (const float*)d_in[17];
    const float* l1ae  = (const float*)d_in[18];
    const float* l1b   = (const float*)d_in[19];
    const float* ln1g  = (const float*)d_in[20];
    const float* ln1b  = (const float*)d_in[21];

    const int N = in_sizes[0] / 6;
    const int E = in_sizes[1] / 2;
    const int E2 = E + N;
    const int* srcI = ei;
    const int* dstI = ei + E;

    char* ws = (char*)d_ws;
    size_t off = 0;
    auto alloc = [&](size_t bytes) -> char* {
        char* p = ws + off;
        off += (bytes + 255) & ~(size_t)255;
        return p;
    };

    float* x0     = (float*)alloc((size_t)N * 256 * 4);   // reused: x1 = first half, h1 = second half
    float* h0     = (float*)alloc((size_t)N * 256 * 4);
    float* as0    = (float*)alloc((size_t)N * 4 * 4);
    float* ad0    = (float*)alloc((size_t)N * 4 * 4);
    float* as1    = (float*)alloc((size_t)N * 4 * 4);
    float* ad1    = (float*)alloc((size_t)N * 4 * 4);
    float* sinv   = (float*)alloc((size_t)N * 4 * 4);
    int*   row_ptr= (int*)alloc((size_t)(N + 1) * 4);
    int*   counts = (int*)alloc((size_t)N * 4);
    int*   cursor = (int*)alloc((size_t)N * 4);
    int*   eids   = (int*)alloc((size_t)E2 * 4);
    int*   srcp   = (int*)alloc((size_t)E2 * 4);
    float4* alphab= (float4*)alloc((size_t)E2 * 16);
    int*   bsum   = (int*)alloc(64 * 4);
    int*   bpre   = (int*)alloc(64 * 4);
    float* epart  = (float*)alloc(256 * 4);
    float* emean  = (float*)alloc(4);
    float* wedot0 = (float*)alloc(16);
    float* wedot1 = (float*)alloc(16);
    int*   gstart = (int*)alloc((NUM_GRAPHS + 1) * 4);
    float* psum   = (float*)alloc((size_t)NUM_GRAPHS * POOL_SPLIT * 128 * 4);
    float* pmax   = (float*)alloc((size_t)NUM_GRAPHS * POOL_SPLIT * 128 * 4);

    float* x1 = x0;                       // [N,128], x0 dead by then
    float* h1 = x0 + (size_t)N * 128;     // [N,128]

    const int B = (N + 1023) / 1024;      // scan chunks

    // --- independent prep ---
    k_prep<<<1, 256, 0, stream>>>(l0We, l0ae, l1We, l1ae, wedot0, wedot1);
    k_esum_partial<<<256, 256, 0, stream>>>(eattr, epart, E);
    k_esum_final<<<1, 256, 0, stream>>>(epart, 256, emean, E);

    // --- CSR build (dst-indexed, deterministic) ---
    k_counts_init<<<(N + 255) / 256, 256, 0, stream>>>(counts, N);
    k_count<<<(E + 255) / 256, 256, 0, stream>>>(dstI, counts, E);
    k_scan_partial<<<B, 256, 0, stream>>>(counts, bsum, N);
    k_scan_bsums<<<1, 64, 0, stream>>>(bsum, bpre, B);
    k_scan_chunk<<<B, 256, 0, stream>>>(counts, bpre, row_ptr, cursor, N, E2);
    k_place<<<(E2 + 255) / 256, 256, 0, stream>>>(dstI, cursor, eids, E, N);
    k_rowsort<<<(N + 255) / 256, 256, 0, stream>>>(row_ptr, eids, N);

    // --- layer 0 ---
    k_gemm0<<<dim3((N + 127) / 128, 2), 256, 0, stream>>>(
        x, Win, bin, l0W, l0as, l0ad, x0, as0, ad0, N);
    k_edgeprep<true><<<(N + 3) / 4, 256, 0, stream>>>(
        row_ptr, eids, srcI, eattr, emean, wedot0, as0, ad0, srcp, alphab, sinv, N, E);
    k_agg<256, 4, true><<<(N + 3) / 4, 256, 0, stream>>>(
        x0, row_ptr, srcp, (const float*)alphab, sinv, l0b, ln0g, ln0b, h0, N);

    // --- layer 1 ---
    k_gemm1<<<(N + 127) / 128, 256, 0, stream>>>(h0, l1W, l1as, l1ad, x1, as1, ad1, N);
    k_edgeprep<false><<<(N + 3) / 4, 256, 0, stream>>>(
        row_ptr, eids, srcI, eattr, emean, wedot1, as1, ad1, srcp, alphab, sinv, N, E);
    k_agg<128, 2, false><<<(N + 3) / 4, 256, 0, stream>>>(
        x1, row_ptr, srcp, (const float*)alphab, sinv, l1b, ln1g, ln1b, h1, N);

    // --- pooling (two-stage) ---
    k_bounds<<<1, 128, 0, stream>>>(batch, gstart, N);
    k_pool1<<<dim3(NUM_GRAPHS, POOL_SPLIT), 128, 0, stream>>>(h1, gstart, psum, pmax);
    k_pool2<<<NUM_GRAPHS, 128, 0, stream>>>(psum, pmax, gstart, (float*)d_out);
}